// Round 10
// baseline (382.848 us; speedup 1.0000x reference)
//
#include <hip/hip_runtime.h>
#include <math.h>

#define BB 32
#define LL 2048
#define EE 512
#define HH 512

typedef __bf16 bf16_t;
typedef bf16_t bf16x8 __attribute__((ext_vector_type(8)));
typedef float f32x4 __attribute__((ext_vector_type(4)));
typedef unsigned short u16x8 __attribute__((ext_vector_type(8)));

#define MFMA __builtin_amdgcn_mfma_f32_16x16x32_bf16

__device__ __forceinline__ unsigned short f2bf(float f) {
  unsigned int u = __builtin_bit_cast(unsigned int, f);
  unsigned int r = (u + 0x7FFFu + ((u >> 16) & 1u)) >> 16;  // RNE
  return (unsigned short)r;
}
__device__ __forceinline__ float bf2f(unsigned short s) {
  unsigned int u = ((unsigned int)s) << 16;
  return __builtin_bit_cast(float, u);
}
__device__ __forceinline__ bf16x8 ld_frag(const unsigned short* p) {
  u16x8 raw = *(const u16x8*)p;
  return __builtin_bit_cast(bf16x8, raw);
}
__device__ __forceinline__ float tanh_fast(float x) {
  x = fminf(fmaxf(x, -15.f), 15.f);
  float e2 = __expf(2.f * x);
  return (e2 - 1.f) / (e2 + 1.f);
}

// encA/hS: 64x512 bf16 tiles, stride 512 (no pad) with T2 XOR swizzle (bits 3-5 of
// the column XORed with row&7) -> b128 column-slice reads spread across bank groups.
__device__ __forceinline__ int swz(int row, int col) {
  return row * 512 + (col ^ ((row & 7) << 3));
}

// sub-slab staging: 32 weight rows x 32 k per step, 2 frags/lane, global->reg->LDS.
__device__ __forceinline__ void w_issue2(const unsigned short* __restrict__ Wt,
                                         int rbase, int k0, int lane, u16x8 t[2]) {
  const unsigned short* g = Wt + (size_t)(rbase + (lane >> 2)) * 512 + k0 + (lane & 3) * 8;
  t[0] = *(const u16x8*)(g);
  t[1] = *(const u16x8*)(g + 16 * 512);
}
__device__ __forceinline__ void w_write2(unsigned short* buf, int lane, const u16x8 t[2]) {
  unsigned short* d = buf + (lane >> 2) * 32 + (lane & 3) * 8;
  *(u16x8*)(d) = t[0];
  *(u16x8*)(d + 16 * 32) = t[1];
}

// One GEMM1 k-window (64 enc rows = TWO paired items): write sub-slab S01, prefetch
// its window+2 replacement, 8 MFMA; same for S23. Per-wave in-order DS makes the
// single 2KB buffer's read->overwrite safe. Each slab frag read feeds 4 MFMAs
// (vs 2 in R7) -> slab LDS traffic and L2 weight stream HALVED per item.
#define G1_WIN(S01, S23, W, PF) do {                                            \
    const int k0_ = (((W) + phase) & 15) * 32;                                  \
    const bf16x8 b0_ = ld_frag(&encA[swz(l15,      k0_ + quad * 8)]);           \
    const bf16x8 b1_ = ld_frag(&encA[swz(16 + l15, k0_ + quad * 8)]);           \
    const bf16x8 b2_ = ld_frag(&encA[swz(32 + l15, k0_ + quad * 8)]);           \
    const bf16x8 b3_ = ld_frag(&encA[swz(48 + l15, k0_ + quad * 8)]);           \
    w_write2(slab, lane, S01);                                                  \
    if (PF) w_issue2(WhT, wbase, (((W) + 2 + phase) & 15) * 32, lane, S01);     \
    {                                                                           \
      const bf16x8 af0_ = ld_frag(&slab[l15 * 32 + quad * 8]);                  \
      const bf16x8 af1_ = ld_frag(&slab[(16 + l15) * 32 + quad * 8]);           \
      acc[0][0] = MFMA(af0_, b0_, acc[0][0], 0, 0, 0);                          \
      acc[0][1] = MFMA(af0_, b1_, acc[0][1], 0, 0, 0);                          \
      acc[0][2] = MFMA(af0_, b2_, acc[0][2], 0, 0, 0);                          \
      acc[0][3] = MFMA(af0_, b3_, acc[0][3], 0, 0, 0);                          \
      acc[1][0] = MFMA(af1_, b0_, acc[1][0], 0, 0, 0);                          \
      acc[1][1] = MFMA(af1_, b1_, acc[1][1], 0, 0, 0);                          \
      acc[1][2] = MFMA(af1_, b2_, acc[1][2], 0, 0, 0);                          \
      acc[1][3] = MFMA(af1_, b3_, acc[1][3], 0, 0, 0);                          \
    }                                                                           \
    w_write2(slab, lane, S23);                                                  \
    if (PF) w_issue2(WhT, wbase + 32, (((W) + 2 + phase) & 15) * 32, lane, S23);\
    {                                                                           \
      const bf16x8 af2_ = ld_frag(&slab[l15 * 32 + quad * 8]);                  \
      const bf16x8 af3_ = ld_frag(&slab[(16 + l15) * 32 + quad * 8]);           \
      acc[2][0] = MFMA(af2_, b0_, acc[2][0], 0, 0, 0);                          \
      acc[2][1] = MFMA(af2_, b1_, acc[2][1], 0, 0, 0);                          \
      acc[2][2] = MFMA(af2_, b2_, acc[2][2], 0, 0, 0);                          \
      acc[2][3] = MFMA(af2_, b3_, acc[2][3], 0, 0, 0);                          \
      acc[3][0] = MFMA(af3_, b0_, acc[3][0], 0, 0, 0);                          \
      acc[3][1] = MFMA(af3_, b1_, acc[3][1], 0, 0, 0);                          \
      acc[3][2] = MFMA(af3_, b2_, acc[3][2], 0, 0, 0);                          \
      acc[3][3] = MFMA(af3_, b3_, acc[3][3], 0, 0, 0);                          \
    }                                                                           \
  } while (0)

#define G2_WIN(S01, S23, W, PF) do {                                            \
    const int k0_ = (((W) + phase) & 15) * 32;                                  \
    const bf16x8 a0_ = ld_frag(&hS[swz(l15,      k0_ + quad * 8)]);             \
    const bf16x8 a1_ = ld_frag(&hS[swz(16 + l15, k0_ + quad * 8)]);             \
    const bf16x8 a2_ = ld_frag(&hS[swz(32 + l15, k0_ + quad * 8)]);             \
    const bf16x8 a3_ = ld_frag(&hS[swz(48 + l15, k0_ + quad * 8)]);             \
    w_write2(slab, lane, S01);                                                  \
    if (PF) w_issue2(WcT, wbase, (((W) + 2 + phase) & 15) * 32, lane, S01);     \
    {                                                                           \
      const bf16x8 cf0_ = ld_frag(&slab[l15 * 32 + quad * 8]);                  \
      const bf16x8 cf1_ = ld_frag(&slab[(16 + l15) * 32 + quad * 8]);           \
      acc[0][0] = MFMA(a0_, cf0_, acc[0][0], 0, 0, 0);                          \
      acc[1][0] = MFMA(a1_, cf0_, acc[1][0], 0, 0, 0);                          \
      acc[2][0] = MFMA(a2_, cf0_, acc[2][0], 0, 0, 0);                          \
      acc[3][0] = MFMA(a3_, cf0_, acc[3][0], 0, 0, 0);                          \
      acc[0][1] = MFMA(a0_, cf1_, acc[0][1], 0, 0, 0);                          \
      acc[1][1] = MFMA(a1_, cf1_, acc[1][1], 0, 0, 0);                          \
      acc[2][1] = MFMA(a2_, cf1_, acc[2][1], 0, 0, 0);                          \
      acc[3][1] = MFMA(a3_, cf1_, acc[3][1], 0, 0, 0);                          \
    }                                                                           \
    w_write2(slab, lane, S23);                                                  \
    if (PF) w_issue2(WcT, wbase + 32, (((W) + 2 + phase) & 15) * 32, lane, S23);\
    {                                                                           \
      const bf16x8 cf2_ = ld_frag(&slab[l15 * 32 + quad * 8]);                  \
      const bf16x8 cf3_ = ld_frag(&slab[(16 + l15) * 32 + quad * 8]);           \
      acc[0][2] = MFMA(a0_, cf2_, acc[0][2], 0, 0, 0);                          \
      acc[1][2] = MFMA(a1_, cf2_, acc[1][2], 0, 0, 0);                          \
      acc[2][2] = MFMA(a2_, cf2_, acc[2][2], 0, 0, 0);                          \
      acc[3][2] = MFMA(a3_, cf2_, acc[3][2], 0, 0, 0);                          \
      acc[0][3] = MFMA(a0_, cf3_, acc[0][3], 0, 0, 0);                          \
      acc[1][3] = MFMA(a1_, cf3_, acc[1][3], 0, 0, 0);                          \
      acc[2][3] = MFMA(a2_, cf3_, acc[2][3], 0, 0, 0);                          \
      acc[3][3] = MFMA(a3_, cf3_, acc[3][3], 0, 0, 0);                          \
    }                                                                           \
  } while (0)

// ---------------- prep: transpose + fp32->bf16 convert of Wh, Wc; init work queue ----------------
__global__ __launch_bounds__(256) void prep_w(
    const float* __restrict__ Wh, const float* __restrict__ Wc,
    unsigned short* __restrict__ WhT, unsigned short* __restrict__ WcT,
    int* __restrict__ q)
{
  if (blockIdx.x == 0 && blockIdx.y == 0 && threadIdx.x == 0) *q = 0;
  const float* src = blockIdx.y ? Wc : Wh;
  unsigned short* dst = blockIdx.y ? WcT : WhT;
  const int tr = (blockIdx.x >> 3) * 64;
  const int tc = (blockIdx.x & 7) * 64;
  const int tid = threadIdx.x;
  __shared__ float tile[64][65];
  for (int i = tid; i < 64 * 16; i += 256) {
    const int r = i >> 4, c4 = (i & 15) << 2;
    const float4 v = *(const float4*)(src + (size_t)(tr + r) * 512 + tc + c4);
    tile[r][c4 + 0] = v.x; tile[r][c4 + 1] = v.y;
    tile[r][c4 + 2] = v.z; tile[r][c4 + 3] = v.w;
  }
  __syncthreads();
  for (int i = tid; i < 64 * 16; i += 256) {
    const int r = i >> 4, c4 = (i & 15) << 2;
    ushort4 pk;
    pk.x = f2bf(tile[c4 + 0][r]); pk.y = f2bf(tile[c4 + 1][r]);
    pk.z = f2bf(tile[c4 + 2][r]); pk.w = f2bf(tile[c4 + 3][r]);
    *(ushort4*)(dst + (size_t)(tc + r) * 512 + tr + c4) = pk;
  }
}

__device__ __forceinline__ int pop_valid(int* q, const int* __restrict__ lens,
                                         int nitems, int Lc) {
  int it;
  for (;;) {
    it = atomicAdd(q, 1);
    if (it >= nitems || lens[it & 31] > (it >> 5) * Lc) return it;
  }
}

// ---------------- main: item pairing (R9) WITHOUT the spill-causing double prefetch ----------------
// R9's structure (two items fused per 64-row joint pass: slab LDS + L2 weight
// stream + barriers HALVED per item) but with register discipline restored:
// only item0's enc tile is prefetched cross-pair (32 f32 regs, R7's exact proven
// live range); item1 is staged synchronously (tmp regs reuse eR's just-freed 32).
// R9's tf0/tf1+eP1 (80 extra live-across-softmax regs) caused 187MB of scratch.
__global__ __launch_bounds__(512, 2) void attn_main(
    const float* __restrict__ enc, const int* __restrict__ lens,
    const unsigned short* __restrict__ WhT, const float* __restrict__ bh,
    const unsigned short* __restrict__ WcT,
    float* __restrict__ pm, float* __restrict__ ps, float* __restrict__ po,
    int* __restrict__ q, int C, int Lc)
{
  const int tid  = threadIdx.x;
  const int wave = tid >> 6;       // 0..7
  const int lane = tid & 63;
  const int quad = lane >> 4;
  const int l15  = lane & 15;
  const int wbase = wave * 64;     // wave's 64-wide h-slab (GEMM1) / e-slab (GEMM2)

  __shared__ __align__(16) unsigned short ebuf[2][64 * 512];  // 2 x 64KB (enc/h ping-pong)
  __shared__ __align__(16) unsigned short wslabS[8][32 * 32]; // 16KB (2KB/wave sub-slab)
  __shared__ __align__(16) float bhS[512];
  __shared__ int itemS[2];

  unsigned short* slab = wslabS[wave];
  bhS[tid] = bh[tid];
  const int nitems = 32 * C;

  // ---- prologue: pop first valid PAIR; prefetch item0's tile only ----
  if (tid == 0) {
    itemS[0] = pop_valid(q, lens, nitems, Lc);
    itemS[1] = pop_valid(q, lens, nitems, Lc);
  }
  __syncthreads();
  int it0 = itemS[0], it1 = itemS[1];
  int pp = 0;

  float4 eR[8];  // item0's next enc tile in flight (32 regs; same live range as R7)
  if (it0 < nitems) {
    const float* src = enc + ((size_t)(it0 & 31) * LL + (size_t)(it0 >> 5) * Lc) * EE;
#pragma unroll
    for (int k = 0; k < 8; k++) {
      const int i = tid + k * 512;
      eR[k] = *(const float4*)(src + (size_t)(i >> 7) * EE + ((i & 127) << 2));
    }
  }

#pragma unroll 1
  for (;;) {
    if (it0 >= nitems) break;
    const int b0i = it0 & 31, c0i = it0 >> 5;
    const int l00 = c0i * Lc;
    const int nv0 = min(lens[b0i] - l00, Lc);    // >= 1 (pop skips invalid)
    int b1i = 0, c1i = 0, l01 = 0, nv1 = 0;
    if (it1 < nitems) { b1i = it1 & 31; c1i = it1 >> 5; l01 = c1i * Lc; nv1 = min(lens[b1i] - l01, Lc); }
    const int nvmax = nv0 > nv1 ? nv0 : nv1;
    const int phase = (it0 + wave) & 15;         // k-window de-phasing
    unsigned short* encA = ebuf[pp];
    unsigned short* hS   = ebuf[pp ^ 1];

    float stM[2][4], stS[2][4], stO[2][4];
#pragma unroll
    for (int h = 0; h < 2; h++)
#pragma unroll
      for (int et = 0; et < 4; et++) { stM[h][et] = -1e30f; stS[h][et] = 0.f; stO[h][et] = 0.f; }

    int nx0 = nitems, nx1 = nitems;

#pragma unroll 1
    for (int r0 = 0; r0 < nvmax; r0 += 32) {
      const bool lastPass = (r0 + 32 >= nvmax);

      // ---- stage: item0 from prefetched eR (frees those 32 regs); item1 synchronous ----
      if (r0 == 0) {
#pragma unroll
        for (int k = 0; k < 8; k++) {
          const int i = tid + k * 512;
          ushort4 pk;
          pk.x = f2bf(eR[k].x); pk.y = f2bf(eR[k].y);
          pk.z = f2bf(eR[k].z); pk.w = f2bf(eR[k].w);
          *(ushort4*)&encA[swz(i >> 7, (i & 127) << 2)] = pk;
        }
        if (it1 < nitems) {
          const float* src = enc + ((size_t)b1i * LL + (size_t)l01) * EE;
          float4 tmp[8];  // reuses eR's just-freed registers
#pragma unroll
          for (int k = 0; k < 8; k++) {
            const int i = tid + k * 512;
            tmp[k] = *(const float4*)(src + (size_t)(i >> 7) * EE + ((i & 127) << 2));
          }
#pragma unroll
          for (int k = 0; k < 8; k++) {
            const int i = tid + k * 512;
            ushort4 pk;
            pk.x = f2bf(tmp[k].x); pk.y = f2bf(tmp[k].y);
            pk.z = f2bf(tmp[k].z); pk.w = f2bf(tmp[k].w);
            *(ushort4*)&encA[swz(32 + (i >> 7), (i & 127) << 2)] = pk;
          }
        }
      } else {
        if (r0 < nv0) {
          const float* encRow = enc + ((size_t)b0i * LL + l00 + r0) * EE;
          for (int i = tid; i < 32 * 128; i += 512) {
            const int m = i >> 7, c4 = (i & 127) << 2;
            const float4 v = *(const float4*)(encRow + (size_t)m * EE + c4);
            ushort4 pk;
            pk.x = f2bf(v.x); pk.y = f2bf(v.y); pk.z = f2bf(v.z); pk.w = f2bf(v.w);
            *(ushort4*)&encA[swz(m, c4)] = pk;
          }
        }
        if (r0 < nv1) {
          const float* encRow = enc + ((size_t)b1i * LL + l01 + r0) * EE;
          for (int i = tid; i < 32 * 128; i += 512) {
            const int m = i >> 7, c4 = (i & 127) << 2;
            const float4 v = *(const float4*)(encRow + (size_t)m * EE + c4);
            ushort4 pk;
            pk.x = f2bf(v.x); pk.y = f2bf(v.y); pk.z = f2bf(v.z); pk.w = f2bf(v.w);
            *(ushort4*)&encA[swz(32 + m, c4)] = pk;
          }
        }
      }
      // pop next pair while others stage; published by the barrier below
      if (lastPass && tid == 0) {
        itemS[0] = pop_valid(q, lens, nitems, Lc);
        itemS[1] = pop_valid(q, lens, nitems, Lc);
      }
      __syncthreads();

      f32x4 acc[4][4];

      // ================= GEMM1: hT[64 x 64rows] per wave, acc[t][mt] =================
#pragma unroll
      for (int i = 0; i < 4; i++)
#pragma unroll
        for (int j = 0; j < 4; j++) acc[i][j] = (f32x4){0.f, 0.f, 0.f, 0.f};
      {
        u16x8 sA01[2], sA23[2], sB01[2], sB23[2];
        w_issue2(WhT, wbase,      ((0 + phase) & 15) * 32, lane, sA01);
        w_issue2(WhT, wbase + 32, ((0 + phase) & 15) * 32, lane, sA23);
        w_issue2(WhT, wbase,      ((1 + phase) & 15) * 32, lane, sB01);
        w_issue2(WhT, wbase + 32, ((1 + phase) & 15) * 32, lane, sB23);
#pragma unroll 1
        for (int kk = 0; kk < 16; kk += 2) {
          G1_WIN(sA01, sA23, kk + 0, kk + 2 < 16);
          G1_WIN(sB01, sB23, kk + 1, kk + 3 < 16);
        }
      }

      // ---- bias + tanh, pack -> hS (swizzled) ----
#pragma unroll
      for (int t = 0; t < 4; t++) {
        const f32x4 bv = *(const f32x4*)&bhS[wbase + t * 16 + quad * 4];
#pragma unroll
        for (int mt = 0; mt < 4; mt++) {
          ushort4 pk;
          pk.x = f2bf(tanh_fast(acc[t][mt][0] + bv[0]));
          pk.y = f2bf(tanh_fast(acc[t][mt][1] + bv[1]));
          pk.z = f2bf(tanh_fast(acc[t][mt][2] + bv[2]));
          pk.w = f2bf(tanh_fast(acc[t][mt][3] + bv[3]));
          *(ushort4*)&hS[swz(mt * 16 + l15, wbase + t * 16 + quad * 4)] = pk;
        }
      }
      __syncthreads();

      // ================= GEMM2: logits[64rows x 64e] per wave, acc[mt][et] =================
#pragma unroll
      for (int i = 0; i < 4; i++)
#pragma unroll
        for (int j = 0; j < 4; j++) acc[i][j] = (f32x4){0.f, 0.f, 0.f, 0.f};
      {
        u16x8 sA01[2], sA23[2], sB01[2], sB23[2];
        w_issue2(WcT, wbase,      ((0 + phase) & 15) * 32, lane, sA01);
        w_issue2(WcT, wbase + 32, ((0 + phase) & 15) * 32, lane, sA23);
        w_issue2(WcT, wbase,      ((1 + phase) & 15) * 32, lane, sB01);
        w_issue2(WcT, wbase + 32, ((1 + phase) & 15) * 32, lane, sB23);
#pragma unroll 1
        for (int kk = 0; kk < 16; kk += 2) {
          G2_WIN(sA01, sA23, kk + 0, kk + 2 < 16);
          G2_WIN(sB01, sB23, kk + 1, kk + 3 < 16);
        }
      }

      // ---- issue NEXT pair item0's enc loads (f32 in flight across softmax, R7 pattern) ----
      if (lastPass) {
        nx0 = itemS[0]; nx1 = itemS[1];
        if (nx0 < nitems) {
          const float* src = enc + ((size_t)(nx0 & 31) * LL + (size_t)(nx0 >> 5) * Lc) * EE;
#pragma unroll
          for (int k = 0; k < 8; k++) {
            const int i = tid + k * 512;
            eR[k] = *(const float4*)(src + (size_t)(i >> 7) * EE + ((i & 127) << 2));
          }
        }
      }

      // ---- masked online softmax, one independent state per item half ----
#pragma unroll
      for (int H = 0; H < 2; H++) {
        const int nvH = H ? nv1 : nv0;
#pragma unroll
        for (int et = 0; et < 4; et++) {
          const int e = wbase + et * 16 + l15;
          float lm = -1e30f;
#pragma unroll
          for (int mi = 0; mi < 2; mi++) {
            const int mt = H * 2 + mi;
#pragma unroll
            for (int r = 0; r < 4; r++) {
              const float vv = (r0 + mi * 16 + quad * 4 + r) < nvH ? acc[mt][et][r] : -1e30f;
              lm = fmaxf(lm, vv);
            }
          }
          lm = fmaxf(lm, __shfl_xor(lm, 16));
          lm = fmaxf(lm, __shfl_xor(lm, 32));
          float ls = 0.f, lo = 0.f;
#pragma unroll
          for (int mi = 0; mi < 2; mi++) {
            const int mt = H * 2 + mi;
#pragma unroll
            for (int r = 0; r < 4; r++) {
              const float vv = (r0 + mi * 16 + quad * 4 + r) < nvH ? acc[mt][et][r] : -1e30f;
              const float pexp = __expf(vv - lm);
              const float ev = bf2f(encA[swz(mt * 16 + quad * 4 + r, e)]);
              ls += pexp;
              lo += pexp * ev;
            }
          }
          ls += __shfl_xor(ls, 16); ls += __shfl_xor(ls, 32);
          lo += __shfl_xor(lo, 16); lo += __shfl_xor(lo, 32);
          const float Mn = fmaxf(stM[H][et], lm);
          const float sc = __expf(stM[H][et] - Mn);
          const float st = __expf(lm - Mn);
          stS[H][et] = stS[H][et] * sc + ls * st;
          stO[H][et] = stO[H][et] * sc + lo * st;
          stM[H][et] = Mn;
        }
      }
      __syncthreads();   // end of pass: all reads of encA/hS complete
    }

    if (quad == 0) {
      const size_t base0 = ((size_t)b0i * C + c0i) * EE;
#pragma unroll
      for (int et = 0; et < 4; et++) {
        const int e = wbase + et * 16 + l15;
        pm[base0 + e] = stM[0][et];
        ps[base0 + e] = stS[0][et];
        po[base0 + e] = stO[0][et];
      }
      if (it1 < nitems) {
        const size_t base1 = ((size_t)b1i * C + c1i) * EE;
#pragma unroll
        for (int et = 0; et < 4; et++) {
          const int e = wbase + et * 16 + l15;
          pm[base1 + e] = stM[1][et];
          ps[base1 + e] = stS[1][et];
          po[base1 + e] = stO[1][et];
        }
      }
    }

    it0 = nx0; it1 = nx1; pp ^= 1;
  }
}

// ---------------- combine over chunks (parallelized: 8 e-slabs x 4 c-groups) ----------------
__global__ __launch_bounds__(256) void attn_combine(
    const float* __restrict__ pm, const float* __restrict__ ps,
    const float* __restrict__ po, const int* __restrict__ lens,
    float* __restrict__ out, int C, int Lc)
{
  const int b  = blockIdx.y;
  const int e  = blockIdx.x * 64 + (threadIdx.x & 63);
  const int g  = threadIdx.x >> 6;  // c-group 0..3
  const int n  = lens[b];
  const int cmax = min(C, (n + Lc - 1) / Lc);

  float M = -1e30f, S = 0.f, O = 0.f;
  for (int c = g; c < cmax; c += 4) {
    const size_t base = ((size_t)b * C + c) * EE;
    const float m = pm[base + e];
    const float s = ps[base + e];
    const float o = po[base + e];
    const float Mn  = fmaxf(M, m);
    const float sc0 = __expf(M - Mn);
    const float sc1 = __expf(m - Mn);
    S = S * sc0 + s * sc1;
    O = O * sc0 + o * sc1;
    M = Mn;
  }

  __shared__ float sM[4][64], sS[4][64], sO[4][64];
  sM[g][threadIdx.x & 63] = M;
  sS[g][threadIdx.x & 63] = S;
  sO[g][threadIdx.x & 63] = O;
  __syncthreads();

  if (g == 0) {
    const int le = threadIdx.x & 63;
    float Mt = sM[0][le], St = sS[0][le], Ot = sO[0][le];
#pragma unroll
    for (int gg = 1; gg < 4; gg++) {
      const float m = sM[gg][le];
      const float Mn  = fmaxf(Mt, m);
      const float sc0 = __expf(Mt - Mn);
      const float sc1 = __expf(m - Mn);
      St = St * sc0 + sS[gg][le] * sc1;
      Ot = Ot * sc0 + sO[gg][le] * sc1;
      Mt = Mn;
    }
    out[(size_t)b * EE + e] = Ot / St;  // St > 0: c=0 always valid (lengths >= 1)
  }
}

extern "C" void kernel_launch(void* const* d_in, const int* in_sizes, int n_in,
                              void* d_out, int out_size, void* d_ws, size_t ws_size,
                              hipStream_t stream) {
  const float* enc  = (const float*)d_in[0];
  const int*   lens = (const int*)d_in[1];
  const float* Wh   = (const float*)d_in[2];
  const float* bh   = (const float*)d_in[3];
  const float* Wc   = (const float*)d_in[4];
  float* out = (float*)d_out;

  const size_t wbytes = (size_t)512 * 512 * sizeof(unsigned short);
  int C = 64;  // Lc=32 -> one 32-row pass per item (pairing fuses two per joint pass)
  while (C > 8 && ws_size < (size_t)3 * BB * C * EE * sizeof(float) + 2 * wbytes + 64)
    C >>= 1;
  const int Lc = LL / C;

  float* pm = (float*)d_ws;
  float* ps = pm + (size_t)BB * C * EE;
  float* po = ps + (size_t)BB * C * EE;
  unsigned short* WhT = (unsigned short*)(po + (size_t)BB * C * EE);
  unsigned short* WcT = WhT + (size_t)512 * 512;
  int* q = (int*)(WcT + (size_t)512 * 512);

  prep_w<<<dim3(64, 2), 256, 0, stream>>>(Wh, Wc, WhT, WcT, q);
  attn_main<<<dim3(512), 512, 0, stream>>>(enc, lens, WhT, bh, WcT, pm, ps, po, q, C, Lc);
  attn_combine<<<dim3(8, BB), 256, 0, stream>>>(pm, ps, po, lens, out, C, Lc);
}

// Round 11
// 275.532 us; speedup vs baseline: 1.3895x; 1.3895x over previous
//
#include <hip/hip_runtime.h>
#include <math.h>

#define BB 32
#define LL 2048
#define EE 512
#define HH 512
#define WSL 32   // packed slab row stride (ushorts): 64B rows. Slot-swizzled (see below):
                 // k-slot s of row r lives at 16B-slot s^((r>>1)&3) -> an 8-lane b128
                 // read group covers all 32 banks (R7's layout was 4-way conflicted:
                 // 6.87M conflict-cycles, ~all from slab reads).

typedef __bf16 bf16_t;
typedef bf16_t bf16x8 __attribute__((ext_vector_type(8)));
typedef float f32x4 __attribute__((ext_vector_type(4)));
typedef unsigned short u16x8 __attribute__((ext_vector_type(8)));

__device__ __forceinline__ unsigned short f2bf(float f) {
  unsigned int u = __builtin_bit_cast(unsigned int, f);
  unsigned int r = (u + 0x7FFFu + ((u >> 16) & 1u)) >> 16;  // RNE
  return (unsigned short)r;
}
__device__ __forceinline__ float bf2f(unsigned short s) {
  unsigned int u = ((unsigned int)s) << 16;
  return __builtin_bit_cast(float, u);
}
__device__ __forceinline__ bf16x8 ld_frag(const unsigned short* p) {
  u16x8 raw = *(const u16x8*)p;
  return __builtin_bit_cast(bf16x8, raw);
}
__device__ __forceinline__ float tanh_fast(float x) {
  x = fminf(fmaxf(x, -15.f), 15.f);
  float e2 = __expf(2.f * x);
  return (e2 - 1.f) / (e2 + 1.f);
}

// issue the 4 global 16B loads for one 64-row x 32-k weight slab (wave-private rows)
__device__ __forceinline__ void w_issue(const unsigned short* __restrict__ Wt,
                                        int rbase, int k0, int lane, u16x8 t[4]) {
  const unsigned short* g = Wt + (size_t)(rbase + (lane >> 2)) * 512 + k0 + (lane & 3) * 8;
#pragma unroll
  for (int i = 0; i < 4; i++) t[i] = *(const u16x8*)(g + i * 16 * 512);
}
// write the slab into this wave's LDS buffer at the SWIZZLED slot. wslot is the
// lane-constant ((lane&3)^((lane>>3)&3))*8: row r=(lane>>2)+16i has (r>>1)&3 ==
// (lane>>3)&3 for all i, so one XOR serves all 4 frags. Still a permutation of
// the sequential pattern within each 64B row -> writes stay conflict-optimal.
__device__ __forceinline__ void w_write(unsigned short* buf, int lane, int wslot,
                                        const u16x8 t[4]) {
  unsigned short* d = buf + (lane >> 2) * WSL + wslot;
#pragma unroll
  for (int i = 0; i < 4; i++) *(u16x8*)(d + i * 16 * WSL) = t[i];
}

// ---------------- prep: transpose + fp32->bf16 convert of Wh, Wc; init work queue ----------------
__global__ __launch_bounds__(256) void prep_w(
    const float* __restrict__ Wh, const float* __restrict__ Wc,
    unsigned short* __restrict__ WhT, unsigned short* __restrict__ WcT,
    int* __restrict__ q)
{
  if (blockIdx.x == 0 && blockIdx.y == 0 && threadIdx.x == 0) *q = 0;
  const float* src = blockIdx.y ? Wc : Wh;
  unsigned short* dst = blockIdx.y ? WcT : WhT;
  const int tr = (blockIdx.x >> 3) * 64;
  const int tc = (blockIdx.x & 7) * 64;
  const int tid = threadIdx.x;
  __shared__ float tile[64][65];
  for (int i = tid; i < 64 * 16; i += 256) {
    const int r = i >> 4, c4 = (i & 15) << 2;
    const float4 v = *(const float4*)(src + (size_t)(tr + r) * 512 + tc + c4);
    tile[r][c4 + 0] = v.x; tile[r][c4 + 1] = v.y;
    tile[r][c4 + 2] = v.z; tile[r][c4 + 3] = v.w;
  }
  __syncthreads();
  for (int i = tid; i < 64 * 16; i += 256) {
    const int r = i >> 4, c4 = (i & 15) << 2;
    ushort4 pk;
    pk.x = f2bf(tile[c4 + 0][r]); pk.y = f2bf(tile[c4 + 1][r]);
    pk.z = f2bf(tile[c4 + 2][r]); pk.w = f2bf(tile[c4 + 3][r]);
    *(ushort4*)(dst + (size_t)(tc + r) * 512 + tr + c4) = pk;
  }
}

// ---------------- main: R7 structure + slab slot-swizzle (bank-conflict fix) ----------------
// R7 (125us, clean 128-VGPR build) verbatim except: slab writes/reads use the
// lane-constant slot XOR. Read row r=t*16+l15 wants k-slot quad, stored at slot
// quad^((l15>>1)&3) ((r>>1)&3 is t-independent) -> rslot hoisted, zero loop VALU.
__global__ __launch_bounds__(512, 2) void attn_main(
    const float* __restrict__ enc, const int* __restrict__ lens,
    const unsigned short* __restrict__ WhT, const float* __restrict__ bh,
    const unsigned short* __restrict__ WcT,
    float* __restrict__ pm, float* __restrict__ ps, float* __restrict__ po,
    int* __restrict__ q, int C, int Lc)
{
  const int tid  = threadIdx.x;
  const int wave = tid >> 6;       // 0..7
  const int lane = tid & 63;
  const int quad = lane >> 4;
  const int l15  = lane & 15;
  const int wbase = wave * 64;     // wave's 64-wide h-slab (GEMM1) / e-slab (GEMM2)

  const int wslot = ((lane & 3) ^ ((lane >> 3) & 3)) * 8;  // write-side slot (ushorts)
  const int rslot = (quad ^ ((l15 >> 1) & 3)) * 8;         // read-side slot (ushorts)

  __shared__ __align__(16) unsigned short ebuf[2][32 * 520];         // 66.6 KB (enc/h ping-pong)
  __shared__ __align__(16) unsigned short wslabS[8 * 2 * 64 * WSL];  // 64 KB
  __shared__ __align__(16) float bhS[512];
  __shared__ int itemS;

  unsigned short* sl0 = &wslabS[(wave * 2 + 0) * 64 * WSL];
  unsigned short* sl1 = &wslabS[(wave * 2 + 1) * 64 * WSL];

  bhS[tid] = bh[tid];
  const int nitems = 32 * C;

  // ---- prologue: pop first VALID item (tid0 skips empty chunks without barriers) ----
  if (tid == 0) {
    int it;
    for (;;) {
      it = atomicAdd(q, 1);
      if (it >= nitems || lens[it & 31] > (it >> 5) * Lc) break;
    }
    itemS = it;
  }
  __syncthreads();
  int item = itemS;
  int p = 0;

  float4 eR[8];  // next enc tile in flight (32 regs; dead during GEMM1/pack)
  if (item < nitems) {
    const float* src = enc + ((size_t)(item & 31) * LL + (size_t)(item >> 5) * Lc) * EE;
#pragma unroll
    for (int k = 0; k < 8; k++) {
      const int i = tid + k * 512;
      eR[k] = *(const float4*)(src + (size_t)(i >> 7) * EE + ((i & 127) << 2));
    }
  }

#pragma unroll 1
  for (;;) {
    if (item >= nitems) break;
    const int b = item & 31;
    const int c = item >> 5;
    const int l0 = c * Lc;
    const int nvalid = min(lens[b] - l0, Lc);   // >= 1 (pop skips invalid)
    const int phase = (item + wave) & 15;       // k-window de-phasing
    unsigned short* encA = ebuf[p];
    unsigned short* hS   = ebuf[p ^ 1];

    float stM[4], stS[4], stO[4];
#pragma unroll
    for (int et = 0; et < 4; et++) { stM[et] = -1e30f; stS[et] = 0.f; stO[et] = 0.f; }

    int nextItem = nitems;

#pragma unroll 1
    for (int r0 = 0; r0 < nvalid; r0 += 32) {
      const bool lastPass = (r0 + 32 >= nvalid);

      // ---- stage: pass 0 writes the PREFETCHED regs; later passes load synchronously ----
      if (r0 == 0) {
#pragma unroll
        for (int k = 0; k < 8; k++) {
          const int i = tid + k * 512;
          const float4 v = eR[k];
          ushort4 pk;
          pk.x = f2bf(v.x); pk.y = f2bf(v.y); pk.z = f2bf(v.z); pk.w = f2bf(v.w);
          *(ushort4*)&encA[(i >> 7) * 520 + ((i & 127) << 2)] = pk;
        }
      } else {
        const float* encRow = enc + ((size_t)b * LL + l0 + r0) * EE;
        for (int i = tid; i < 32 * 128; i += 512) {
          const int m = i >> 7, e4 = (i & 127) << 2;
          const float4 v = *(const float4*)(encRow + (size_t)m * EE + e4);
          ushort4 pk;
          pk.x = f2bf(v.x); pk.y = f2bf(v.y); pk.z = f2bf(v.z); pk.w = f2bf(v.w);
          *(ushort4*)&encA[m * 520 + e4] = pk;
        }
      }
      // pop next valid item while others stage; published by the barrier below
      if (lastPass && tid == 0) {
        int it;
        for (;;) {
          it = atomicAdd(q, 1);
          if (it >= nitems || lens[it & 31] > (it >> 5) * Lc) break;
        }
        itemS = it;
      }
      __syncthreads();

      // ================= GEMM1: hT[64 x 32] per wave = WhT @ encT (slab dance) =================
      f32x4 acc1[4][2];
#pragma unroll
      for (int t = 0; t < 4; t++)
        for (int mt = 0; mt < 2; mt++) acc1[t][mt] = (f32x4){0.f, 0.f, 0.f, 0.f};
      {
        u16x8 tA[4], tB[4];
        w_issue(WhT, wbase, ((0 + phase) & 15) * 32, lane, tA);
        w_issue(WhT, wbase, ((1 + phase) & 15) * 32, lane, tB);
        w_write(sl0, lane, wslot, tA);    // waits only tA's loads; tB stays in flight
#pragma unroll 1
        for (int kk = 0; kk < 16; kk += 2) {
          w_write(sl1, lane, wslot, tB);
          if (kk + 2 < 16) w_issue(WhT, wbase, ((kk + 2 + phase) & 15) * 32, lane, tA);
          {
            const int k0 = ((kk + phase) & 15) * 32;
            const bf16x8 b0 = ld_frag(&encA[l15 * 520 + k0 + quad * 8]);
            const bf16x8 b1 = ld_frag(&encA[(16 + l15) * 520 + k0 + quad * 8]);
#pragma unroll
            for (int t = 0; t < 4; t++) {
              const bf16x8 af = ld_frag(&sl0[(t * 16 + l15) * WSL + rslot]);
              acc1[t][0] = __builtin_amdgcn_mfma_f32_16x16x32_bf16(af, b0, acc1[t][0], 0, 0, 0);
              acc1[t][1] = __builtin_amdgcn_mfma_f32_16x16x32_bf16(af, b1, acc1[t][1], 0, 0, 0);
            }
          }
          if (kk + 2 < 16) w_write(sl0, lane, wslot, tA);
          if (kk + 3 < 16) w_issue(WhT, wbase, ((kk + 3 + phase) & 15) * 32, lane, tB);
          {
            const int k0 = ((kk + 1 + phase) & 15) * 32;
            const bf16x8 b0 = ld_frag(&encA[l15 * 520 + k0 + quad * 8]);
            const bf16x8 b1 = ld_frag(&encA[(16 + l15) * 520 + k0 + quad * 8]);
#pragma unroll
            for (int t = 0; t < 4; t++) {
              const bf16x8 af = ld_frag(&sl1[(t * 16 + l15) * WSL + rslot]);
              acc1[t][0] = __builtin_amdgcn_mfma_f32_16x16x32_bf16(af, b0, acc1[t][0], 0, 0, 0);
              acc1[t][1] = __builtin_amdgcn_mfma_f32_16x16x32_bf16(af, b1, acc1[t][1], 0, 0, 0);
            }
          }
        }
      }

      // ---- bias + tanh, pack 4 consecutive h -> one 8B LDS write of h[m][h] ----
#pragma unroll
      for (int t = 0; t < 4; t++) {
        const f32x4 bv = *(const f32x4*)&bhS[wbase + t * 16 + quad * 4];
#pragma unroll
        for (int mt = 0; mt < 2; mt++) {
          ushort4 pk;
          pk.x = f2bf(tanh_fast(acc1[t][mt][0] + bv[0]));
          pk.y = f2bf(tanh_fast(acc1[t][mt][1] + bv[1]));
          pk.z = f2bf(tanh_fast(acc1[t][mt][2] + bv[2]));
          pk.w = f2bf(tanh_fast(acc1[t][mt][3] + bv[3]));
          *(ushort4*)&hS[(mt * 16 + l15) * 520 + wbase + t * 16 + quad * 4] = pk;
        }
      }
      __syncthreads();

      // ================= GEMM2: logits[32 x 64] per wave = h @ WcT-slab =================
      f32x4 acc2[2][4];
#pragma unroll
      for (int mt = 0; mt < 2; mt++)
        for (int et = 0; et < 4; et++) acc2[mt][et] = (f32x4){0.f, 0.f, 0.f, 0.f};
      {
        u16x8 tA[4], tB[4];
        w_issue(WcT, wbase, ((0 + phase) & 15) * 32, lane, tA);
        w_issue(WcT, wbase, ((1 + phase) & 15) * 32, lane, tB);
        w_write(sl0, lane, wslot, tA);
#pragma unroll 1
        for (int kk = 0; kk < 16; kk += 2) {
          w_write(sl1, lane, wslot, tB);
          if (kk + 2 < 16) w_issue(WcT, wbase, ((kk + 2 + phase) & 15) * 32, lane, tA);
          {
            const int k0 = ((kk + phase) & 15) * 32;
            const bf16x8 a0 = ld_frag(&hS[l15 * 520 + k0 + quad * 8]);
            const bf16x8 a1 = ld_frag(&hS[(16 + l15) * 520 + k0 + quad * 8]);
#pragma unroll
            for (int et = 0; et < 4; et++) {
              const bf16x8 bf = ld_frag(&sl0[(et * 16 + l15) * WSL + rslot]);
              acc2[0][et] = __builtin_amdgcn_mfma_f32_16x16x32_bf16(a0, bf, acc2[0][et], 0, 0, 0);
              acc2[1][et] = __builtin_amdgcn_mfma_f32_16x16x32_bf16(a1, bf, acc2[1][et], 0, 0, 0);
            }
          }
          if (kk + 2 < 16) w_write(sl0, lane, wslot, tA);
          if (kk + 3 < 16) w_issue(WcT, wbase, ((kk + 3 + phase) & 15) * 32, lane, tB);
          {
            const int k0 = ((kk + 1 + phase) & 15) * 32;
            const bf16x8 a0 = ld_frag(&hS[l15 * 520 + k0 + quad * 8]);
            const bf16x8 a1 = ld_frag(&hS[(16 + l15) * 520 + k0 + quad * 8]);
#pragma unroll
            for (int et = 0; et < 4; et++) {
              const bf16x8 bf = ld_frag(&sl1[(et * 16 + l15) * WSL + rslot]);
              acc2[0][et] = __builtin_amdgcn_mfma_f32_16x16x32_bf16(a0, bf, acc2[0][et], 0, 0, 0);
              acc2[1][et] = __builtin_amdgcn_mfma_f32_16x16x32_bf16(a1, bf, acc2[1][et], 0, 0, 0);
            }
          }
        }
      }

      // ---- issue NEXT item's enc loads (newest in vmcnt FIFO; latency hides under softmax) ----
      if (lastPass) {
        nextItem = itemS;
        if (nextItem < nitems) {
          const float* src = enc + ((size_t)(nextItem & 31) * LL + (size_t)(nextItem >> 5) * Lc) * EE;
#pragma unroll
          for (int k = 0; k < 8; k++) {
            const int i = tid + k * 512;
            eR[k] = *(const float4*)(src + (size_t)(i >> 7) * EE + ((i & 127) << 2));
          }
        }
      }

      // ---- masked online softmax over the 32 time rows of this pass ----
      bool ok[2][4];
#pragma unroll
      for (int mt = 0; mt < 2; mt++)
#pragma unroll
        for (int r = 0; r < 4; r++)
          ok[mt][r] = (r0 + mt * 16 + quad * 4 + r) < nvalid;

#pragma unroll
      for (int et = 0; et < 4; et++) {
        const int e = wbase + et * 16 + l15;
        float v[2][4];
        float lm = -1e30f;
#pragma unroll
        for (int mt = 0; mt < 2; mt++)
#pragma unroll
          for (int r = 0; r < 4; r++) {
            v[mt][r] = ok[mt][r] ? acc2[mt][et][r] : -1e30f;
            lm = fmaxf(lm, v[mt][r]);
          }
        lm = fmaxf(lm, __shfl_xor(lm, 16));
        lm = fmaxf(lm, __shfl_xor(lm, 32));
        float ls = 0.f, lo = 0.f;
#pragma unroll
        for (int mt = 0; mt < 2; mt++)
#pragma unroll
          for (int r = 0; r < 4; r++) {
            const float pexp = __expf(v[mt][r] - lm);
            const float ev = bf2f(encA[(mt * 16 + quad * 4 + r) * 520 + e]);
            ls += pexp;
            lo += pexp * ev;
          }
        ls += __shfl_xor(ls, 16); ls += __shfl_xor(ls, 32);
        lo += __shfl_xor(lo, 16); lo += __shfl_xor(lo, 32);
        const float Mn = fmaxf(stM[et], lm);
        const float sc = __expf(stM[et] - Mn);
        const float st = __expf(lm - Mn);
        stS[et] = stS[et] * sc + ls * st;
        stO[et] = stO[et] * sc + lo * st;
        stM[et] = Mn;
      }
      __syncthreads();   // end of pass: all reads of encA/hS complete
    }

    if (quad == 0) {
      const size_t base = ((size_t)b * C + c) * EE;
#pragma unroll
      for (int et = 0; et < 4; et++) {
        const int e = wbase + et * 16 + l15;
        pm[base + e] = stM[et];
        ps[base + e] = stS[et];
        po[base + e] = stO[et];
      }
    }

    item = nextItem;
    p ^= 1;
  }
}

// ---------------- combine over chunks (parallelized: 8 e-slabs x 4 c-groups) ----------------
__global__ __launch_bounds__(256) void attn_combine(
    const float* __restrict__ pm, const float* __restrict__ ps,
    const float* __restrict__ po, const int* __restrict__ lens,
    float* __restrict__ out, int C, int Lc)
{
  const int b  = blockIdx.y;
  const int e  = blockIdx.x * 64 + (threadIdx.x & 63);
  const int g  = threadIdx.x >> 6;  // c-group 0..3
  const int n  = lens[b];
  const int cmax = min(C, (n + Lc - 1) / Lc);

  float M = -1e30f, S = 0.f, O = 0.f;
  for (int c = g; c < cmax; c += 4) {
    const size_t base = ((size_t)b * C + c) * EE;
    const float m = pm[base + e];
    const float s = ps[base + e];
    const float o = po[base + e];
    const float Mn  = fmaxf(M, m);
    const float sc0 = __expf(M - Mn);
    const float sc1 = __expf(m - Mn);
    S = S * sc0 + s * sc1;
    O = O * sc0 + o * sc1;
    M = Mn;
  }

  __shared__ float sM[4][64], sS[4][64], sO[4][64];
  sM[g][threadIdx.x & 63] = M;
  sS[g][threadIdx.x & 63] = S;
  sO[g][threadIdx.x & 63] = O;
  __syncthreads();

  if (g == 0) {
    const int le = threadIdx.x & 63;
    float Mt = sM[0][le], St = sS[0][le], Ot = sO[0][le];
#pragma unroll
    for (int gg = 1; gg < 4; gg++) {
      const float m = sM[gg][le];
      const float Mn  = fmaxf(Mt, m);
      const float sc0 = __expf(Mt - Mn);
      const float sc1 = __expf(m - Mn);
      St = St * sc0 + sS[gg][le] * sc1;
      Ot = Ot * sc0 + sO[gg][le] * sc1;
      Mt = Mn;
    }
    out[(size_t)b * EE + e] = Ot / St;  // St > 0: c=0 always valid (lengths >= 1)
  }
}

extern "C" void kernel_launch(void* const* d_in, const int* in_sizes, int n_in,
                              void* d_out, int out_size, void* d_ws, size_t ws_size,
                              hipStream_t stream) {
  const float* enc  = (const float*)d_in[0];
  const int*   lens = (const int*)d_in[1];
  const float* Wh   = (const float*)d_in[2];
  const float* bh   = (const float*)d_in[3];
  const float* Wc   = (const float*)d_in[4];
  float* out = (float*)d_out;

  const size_t wbytes = (size_t)512 * 512 * sizeof(unsigned short);
  int C = 64;  // Lc=32 -> one 32-row pass per item
  while (C > 8 && ws_size < (size_t)3 * BB * C * EE * sizeof(float) + 2 * wbytes + 64)
    C >>= 1;
  const int Lc = LL / C;

  float* pm = (float*)d_ws;
  float* ps = pm + (size_t)BB * C * EE;
  float* po = ps + (size_t)BB * C * EE;
  unsigned short* WhT = (unsigned short*)(po + (size_t)BB * C * EE);
  unsigned short* WcT = WhT + (size_t)512 * 512;
  int* q = (int*)(WcT + (size_t)512 * 512);

  prep_w<<<dim3(64, 2), 256, 0, stream>>>(Wh, Wc, WhT, WcT, q);
  attn_main<<<dim3(512), 512, 0, stream>>>(enc, lens, WhT, bh, WcT, pm, ps, po, q, C, Lc);
  attn_combine<<<dim3(8, BB), 256, 0, stream>>>(pm, ps, po, lens, out, C, Lc);
}

// Round 12
// 260.838 us; speedup vs baseline: 1.4678x; 1.0563x over previous
//
#include <hip/hip_runtime.h>
#include <math.h>

#define BB 32
#define LL 2048
#define EE 512
#define HH 512
#define WSL 32   // slab row stride (ushorts) = 64B rows; slot-swizzled (R11-verified):
                 // k-slot s of row r lives at 16B-slot s^((r>>1)&3) -> conflict-free b128 reads.

typedef __bf16 bf16_t;
typedef bf16_t bf16x8 __attribute__((ext_vector_type(8)));
typedef float f32x4 __attribute__((ext_vector_type(4)));
typedef unsigned short u16x8 __attribute__((ext_vector_type(8)));

#define MFMA __builtin_amdgcn_mfma_f32_16x16x32_bf16

__device__ __forceinline__ unsigned short f2bf(float f) {
  unsigned int u = __builtin_bit_cast(unsigned int, f);
  unsigned int r = (u + 0x7FFFu + ((u >> 16) & 1u)) >> 16;  // RNE
  return (unsigned short)r;
}
__device__ __forceinline__ float bf2f(unsigned short s) {
  unsigned int u = ((unsigned int)s) << 16;
  return __builtin_bit_cast(float, u);
}
__device__ __forceinline__ bf16x8 ld_frag(const unsigned short* p) {
  u16x8 raw = *(const u16x8*)p;
  return __builtin_bit_cast(bf16x8, raw);
}
__device__ __forceinline__ float tanh_fast(float x) {
  x = fminf(fmaxf(x, -15.f), 15.f);
  float e2 = __expf(2.f * x);
  return (e2 - 1.f) / (e2 + 1.f);
}

// encA/hS: 64x512 bf16 tiles, stride 512 (no pad) with T2 XOR swizzle: bits 3-5 of
// the column XORed with row&7. b128 column-slice reads stay at the free 2-lane/bank
// minimum (verified R9/R10 correctness-wise); saves the 8KB pad -> LDS budget fits.
__device__ __forceinline__ int swz(int row, int col) {
  return row * 512 + (col ^ ((row & 7) << 3));
}

// 32-row x 32-k weight slab staged global->reg->LDS, 2 frags/lane.
__device__ __forceinline__ void w_issue2(const unsigned short* __restrict__ Wt,
                                         int rbase, int k0, int lane, u16x8 t[2]) {
  const unsigned short* g = Wt + (size_t)(rbase + (lane >> 2)) * 512 + k0 + (lane & 3) * 8;
  t[0] = *(const u16x8*)(g);
  t[1] = *(const u16x8*)(g + 16 * 512);
}
__device__ __forceinline__ void w_write2(unsigned short* buf, int lane, int wslot,
                                         const u16x8 t[2]) {
  unsigned short* d = buf + (lane >> 2) * WSL + wslot;
  *(u16x8*)(d) = t[0];
  *(u16x8*)(d + 16 * WSL) = t[1];
}

// One GEMM1 k-window: write sub-slab S (waits its loads), re-issue S's window+2
// replacement, then 4 encA B-frags x 2 slab A-frags -> 8 MFMA. Single 2KB LDS
// buffer is safe per-wave (in-order DS; R9/R10-verified). acc[t*4+mt].
#define G1_STEP(S, W, PF) do {                                                  \
    w_write2(slab, lane, wslot, S);                                             \
    if (PF) w_issue2(WhT, wb, (((W) + 2 + phase) & 15) * 32, lane, S);          \
    const int k0_ = (((W) + phase) & 15) * 32;                                  \
    const bf16x8 b0_ = ld_frag(&encA[swz(l15,      k0_ + quad * 8)]);           \
    const bf16x8 b1_ = ld_frag(&encA[swz(16 + l15, k0_ + quad * 8)]);           \
    const bf16x8 b2_ = ld_frag(&encA[swz(32 + l15, k0_ + quad * 8)]);           \
    const bf16x8 b3_ = ld_frag(&encA[swz(48 + l15, k0_ + quad * 8)]);           \
    const bf16x8 af0_ = ld_frag(&slab[l15 * WSL + rslot]);                      \
    const bf16x8 af1_ = ld_frag(&slab[(16 + l15) * WSL + rslot]);               \
    acc[0] = MFMA(af0_, b0_, acc[0], 0, 0, 0);                                  \
    acc[1] = MFMA(af0_, b1_, acc[1], 0, 0, 0);                                  \
    acc[2] = MFMA(af0_, b2_, acc[2], 0, 0, 0);                                  \
    acc[3] = MFMA(af0_, b3_, acc[3], 0, 0, 0);                                  \
    acc[4] = MFMA(af1_, b0_, acc[4], 0, 0, 0);                                  \
    acc[5] = MFMA(af1_, b1_, acc[5], 0, 0, 0);                                  \
    acc[6] = MFMA(af1_, b2_, acc[6], 0, 0, 0);                                  \
    acc[7] = MFMA(af1_, b3_, acc[7], 0, 0, 0);                                  \
  } while (0)

// GEMM2 k-window: 4 hS A-frags x 2 WcT slab B-frags. acc[mt*2+et].
#define G2_STEP(S, W, PF) do {                                                  \
    w_write2(slab, lane, wslot, S);                                             \
    if (PF) w_issue2(WcT, wb, (((W) + 2 + phase) & 15) * 32, lane, S);          \
    const int k0_ = (((W) + phase) & 15) * 32;                                  \
    const bf16x8 a0_ = ld_frag(&hS[swz(l15,      k0_ + quad * 8)]);             \
    const bf16x8 a1_ = ld_frag(&hS[swz(16 + l15, k0_ + quad * 8)]);             \
    const bf16x8 a2_ = ld_frag(&hS[swz(32 + l15, k0_ + quad * 8)]);             \
    const bf16x8 a3_ = ld_frag(&hS[swz(48 + l15, k0_ + quad * 8)]);             \
    const bf16x8 cf0_ = ld_frag(&slab[l15 * WSL + rslot]);                      \
    const bf16x8 cf1_ = ld_frag(&slab[(16 + l15) * WSL + rslot]);               \
    acc[0] = MFMA(a0_, cf0_, acc[0], 0, 0, 0);                                  \
    acc[1] = MFMA(a0_, cf1_, acc[1], 0, 0, 0);                                  \
    acc[2] = MFMA(a1_, cf0_, acc[2], 0, 0, 0);                                  \
    acc[3] = MFMA(a1_, cf1_, acc[3], 0, 0, 0);                                  \
    acc[4] = MFMA(a2_, cf0_, acc[4], 0, 0, 0);                                  \
    acc[5] = MFMA(a2_, cf1_, acc[5], 0, 0, 0);                                  \
    acc[6] = MFMA(a3_, cf0_, acc[6], 0, 0, 0);                                  \
    acc[7] = MFMA(a3_, cf1_, acc[7], 0, 0, 0);                                  \
  } while (0)

// ---------------- prep: transpose + fp32->bf16 convert of Wh, Wc; init work queue ----------------
__global__ __launch_bounds__(256) void prep_w(
    const float* __restrict__ Wh, const float* __restrict__ Wc,
    unsigned short* __restrict__ WhT, unsigned short* __restrict__ WcT,
    int* __restrict__ q)
{
  if (blockIdx.x == 0 && blockIdx.y == 0 && threadIdx.x == 0) *q = 0;
  const float* src = blockIdx.y ? Wc : Wh;
  unsigned short* dst = blockIdx.y ? WcT : WhT;
  const int tr = (blockIdx.x >> 3) * 64;
  const int tc = (blockIdx.x & 7) * 64;
  const int tid = threadIdx.x;
  __shared__ float tile[64][65];
  for (int i = tid; i < 64 * 16; i += 256) {
    const int r = i >> 4, c4 = (i & 15) << 2;
    const float4 v = *(const float4*)(src + (size_t)(tr + r) * 512 + tc + c4);
    tile[r][c4 + 0] = v.x; tile[r][c4 + 1] = v.y;
    tile[r][c4 + 2] = v.z; tile[r][c4 + 3] = v.w;
  }
  __syncthreads();
  for (int i = tid; i < 64 * 16; i += 256) {
    const int r = i >> 4, c4 = (i & 15) << 2;
    ushort4 pk;
    pk.x = f2bf(tile[c4 + 0][r]); pk.y = f2bf(tile[c4 + 1][r]);
    pk.z = f2bf(tile[c4 + 2][r]); pk.w = f2bf(tile[c4 + 3][r]);
    *(ushort4*)(dst + (size_t)(tc + r) * 512 + tr + c4) = pk;
  }
}

__device__ __forceinline__ int pop_valid(int* q, const int* __restrict__ lens,
                                         int nitems, int Lc) {
  int it;
  for (;;) {
    it = atomicAdd(q, 1);
    if (it >= nitems || lens[it & 31] > (it >> 5) * Lc) return it;
  }
}

// ---------------- main: 64-row items, per-wave 32-col halves (weight stream halved/row) ----------------
// Pairing's traffic win at R7's register shape: per GEMM, each wave does TWO
// sequential 32-col halves over the 64-row tile. acc = 8 f32x4 = 32 AGPR (R7-equal);
// slab staging 16 regs (half of R7). Per 64 rows: 1MB weight L2 stream (was 2MB),
// 3 barriers (was 6). Items are single-pass -> no online merge; softmax writes
// pm/ps/po directly.
__global__ __launch_bounds__(512, 2) void attn_main(
    const float* __restrict__ enc, const int* __restrict__ lens,
    const unsigned short* __restrict__ WhT, const float* __restrict__ bh,
    const unsigned short* __restrict__ WcT,
    float* __restrict__ pm, float* __restrict__ ps, float* __restrict__ po,
    int* __restrict__ q, int C, int Lc)
{
  const int tid  = threadIdx.x;
  const int wave = tid >> 6;       // 0..7
  const int lane = tid & 63;
  const int quad = lane >> 4;
  const int l15  = lane & 15;

  const int wslot = ((lane & 3) ^ ((lane >> 3) & 3)) * 8;  // slab write slot (R11-verified)
  const int rslot = (quad ^ ((l15 >> 1) & 3)) * 8;         // slab read slot

  __shared__ __align__(16) unsigned short ebuf[2][64 * 512];  // 2 x 64KB (enc/h ping-pong)
  __shared__ __align__(16) unsigned short wslabS[8][32 * WSL];// 16KB (2KB/wave single buffer)
  __shared__ __align__(16) float bhS[512];
  __shared__ int itemS;

  unsigned short* slab = wslabS[wave];
  bhS[tid] = bh[tid];
  const int nitems = 32 * C;

  // ---- prologue: pop first valid item; prefetch its rows 0-31 ----
  if (tid == 0) itemS = pop_valid(q, lens, nitems, Lc);
  __syncthreads();
  int item = itemS;
  int p = 0;

  float4 eR[8];  // next item's enc rows 0-31 in flight (32 regs, R7's proven live range)
  if (item < nitems) {
    const float* src = enc + ((size_t)(item & 31) * LL + (size_t)(item >> 5) * Lc) * EE;
#pragma unroll
    for (int k = 0; k < 8; k++) {
      const int i = tid + k * 512;
      eR[k] = *(const float4*)(src + (size_t)(i >> 7) * EE + ((i & 127) << 2));
    }
  }

#pragma unroll 1
  for (;;) {
    if (item >= nitems) break;
    const int b = item & 31;
    const int c = item >> 5;
    const int l0 = c * Lc;
    const int nvalid = min(lens[b] - l0, Lc);   // 1..64 (pop skips invalid)
    const int phase = (item + wave) & 15;       // k-window de-phasing
    unsigned short* encA = ebuf[p];
    unsigned short* hS   = ebuf[p ^ 1];

    // ---- stage rows 0-31 from prefetch; rows 32-63 synchronously (tmp reuses eR's regs) ----
#pragma unroll
    for (int k = 0; k < 8; k++) {
      const int i = tid + k * 512;
      ushort4 pk;
      pk.x = f2bf(eR[k].x); pk.y = f2bf(eR[k].y);
      pk.z = f2bf(eR[k].z); pk.w = f2bf(eR[k].w);
      *(ushort4*)&encA[swz(i >> 7, (i & 127) << 2)] = pk;
    }
    {
      const float* encRow = enc + ((size_t)b * LL + l0 + 32) * EE;  // always in-bounds (l0+64<=2048)
      float4 tmp[8];
#pragma unroll
      for (int k = 0; k < 8; k++) {
        const int i = tid + k * 512;
        tmp[k] = *(const float4*)(encRow + (size_t)(i >> 7) * EE + ((i & 127) << 2));
      }
#pragma unroll
      for (int k = 0; k < 8; k++) {
        const int i = tid + k * 512;
        ushort4 pk;
        pk.x = f2bf(tmp[k].x); pk.y = f2bf(tmp[k].y);
        pk.z = f2bf(tmp[k].z); pk.w = f2bf(tmp[k].w);
        *(ushort4*)&encA[swz(32 + (i >> 7), (i & 127) << 2)] = pk;
      }
    }
    if (tid == 0) itemS = pop_valid(q, lens, nitems, Lc);
    __syncthreads();

    f32x4 acc[8];

    // ================= GEMM1: two 32-col halves over the 64-row tile =================
#pragma unroll
    for (int h = 0; h < 2; h++) {
      const int wb = h * 256 + wave * 32;
#pragma unroll
      for (int i = 0; i < 8; i++) acc[i] = (f32x4){0.f, 0.f, 0.f, 0.f};
      {
        u16x8 sA[2], sB[2];
        w_issue2(WhT, wb, ((0 + phase) & 15) * 32, lane, sA);
        w_issue2(WhT, wb, ((1 + phase) & 15) * 32, lane, sB);
#pragma unroll 1
        for (int kk = 0; kk < 16; kk += 2) {
          G1_STEP(sA, kk + 0, kk + 2 < 16);
          G1_STEP(sB, kk + 1, kk + 3 < 16);
        }
      }
      // bias + tanh, pack into hS cols [wb, wb+32)
#pragma unroll
      for (int t = 0; t < 2; t++) {
        const f32x4 bv = *(const f32x4*)&bhS[wb + t * 16 + quad * 4];
#pragma unroll
        for (int mt = 0; mt < 4; mt++) {
          ushort4 pk;
          pk.x = f2bf(tanh_fast(acc[t * 4 + mt][0] + bv[0]));
          pk.y = f2bf(tanh_fast(acc[t * 4 + mt][1] + bv[1]));
          pk.z = f2bf(tanh_fast(acc[t * 4 + mt][2] + bv[2]));
          pk.w = f2bf(tanh_fast(acc[t * 4 + mt][3] + bv[3]));
          *(ushort4*)&hS[swz(mt * 16 + l15, wb + t * 16 + quad * 4)] = pk;
        }
      }
    }
    __syncthreads();

    // ================= GEMM2 halves + softmax (single-pass: direct output) =================
    int nextItem = nitems;
    const size_t obase = ((size_t)b * C + c) * EE;
#pragma unroll
    for (int h = 0; h < 2; h++) {
      const int wb = h * 256 + wave * 32;
#pragma unroll
      for (int i = 0; i < 8; i++) acc[i] = (f32x4){0.f, 0.f, 0.f, 0.f};
      {
        u16x8 sA[2], sB[2];
        w_issue2(WcT, wb, ((0 + phase) & 15) * 32, lane, sA);
        w_issue2(WcT, wb, ((1 + phase) & 15) * 32, lane, sB);
#pragma unroll 1
        for (int kk = 0; kk < 16; kk += 2) {
          G2_STEP(sA, kk + 0, kk + 2 < 16);
          G2_STEP(sB, kk + 1, kk + 3 < 16);
        }
      }
      if (h == 1) {  // issue next item's rows 0-31 (latency hides under softmax half B)
        nextItem = itemS;
        if (nextItem < nitems) {
          const float* src = enc + ((size_t)(nextItem & 31) * LL + (size_t)(nextItem >> 5) * Lc) * EE;
#pragma unroll
          for (int k = 0; k < 8; k++) {
            const int i = tid + k * 512;
            eR[k] = *(const float4*)(src + (size_t)(i >> 7) * EE + ((i & 127) << 2));
          }
        }
      }
      // masked softmax over the 64 rows for this half's 32 e-cols
#pragma unroll
      for (int et = 0; et < 2; et++) {
        const int e = wb + et * 16 + l15;
        float lm = -1e30f;
#pragma unroll
        for (int mt = 0; mt < 4; mt++)
#pragma unroll
          for (int r = 0; r < 4; r++) {
            const float vv = (mt * 16 + quad * 4 + r) < nvalid ? acc[mt * 2 + et][r] : -1e30f;
            lm = fmaxf(lm, vv);
          }
        lm = fmaxf(lm, __shfl_xor(lm, 16));
        lm = fmaxf(lm, __shfl_xor(lm, 32));
        float ls = 0.f, lo = 0.f;
#pragma unroll
        for (int mt = 0; mt < 4; mt++)
#pragma unroll
          for (int r = 0; r < 4; r++) {
            const float vv = (mt * 16 + quad * 4 + r) < nvalid ? acc[mt * 2 + et][r] : -1e30f;
            const float pexp = __expf(vv - lm);
            const float ev = bf2f(encA[swz(mt * 16 + quad * 4 + r, e)]);
            ls += pexp;
            lo += pexp * ev;
          }
        ls += __shfl_xor(ls, 16); ls += __shfl_xor(ls, 32);
        lo += __shfl_xor(lo, 16); lo += __shfl_xor(lo, 32);
        if (quad == 0) {
          pm[obase + e] = lm;
          ps[obase + e] = ls;
          po[obase + e] = lo;
        }
      }
    }
    __syncthreads();   // end of item: all reads of encA/hS complete before ping-pong flip

    item = nextItem;
    p ^= 1;
  }
}

// ---------------- combine over chunks (parallelized: 8 e-slabs x 4 c-groups) ----------------
__global__ __launch_bounds__(256) void attn_combine(
    const float* __restrict__ pm, const float* __restrict__ ps,
    const float* __restrict__ po, const int* __restrict__ lens,
    float* __restrict__ out, int C, int Lc)
{
  const int b  = blockIdx.y;
  const int e  = blockIdx.x * 64 + (threadIdx.x & 63);
  const int g  = threadIdx.x >> 6;  // c-group 0..3
  const int n  = lens[b];
  const int cmax = min(C, (n + Lc - 1) / Lc);

  float M = -1e30f, S = 0.f, O = 0.f;
  for (int c = g; c < cmax; c += 4) {
    const size_t base = ((size_t)b * C + c) * EE;
    const float m = pm[base + e];
    const float s = ps[base + e];
    const float o = po[base + e];
    const float Mn  = fmaxf(M, m);
    const float sc0 = __expf(M - Mn);
    const float sc1 = __expf(m - Mn);
    S = S * sc0 + s * sc1;
    O = O * sc0 + o * sc1;
    M = Mn;
  }

  __shared__ float sM[4][64], sS[4][64], sO[4][64];
  sM[g][threadIdx.x & 63] = M;
  sS[g][threadIdx.x & 63] = S;
  sO[g][threadIdx.x & 63] = O;
  __syncthreads();

  if (g == 0) {
    const int le = threadIdx.x & 63;
    float Mt = sM[0][le], St = sS[0][le], Ot = sO[0][le];
#pragma unroll
    for (int gg = 1; gg < 4; gg++) {
      const float m = sM[gg][le];
      const float Mn  = fmaxf(Mt, m);
      const float sc0 = __expf(Mt - Mn);
      const float sc1 = __expf(m - Mn);
      St = St * sc0 + sS[gg][le] * sc1;
      Ot = Ot * sc0 + sO[gg][le] * sc1;
      Mt = Mn;
    }
    out[(size_t)b * EE + e] = Ot / St;  // St > 0: c=0 always valid (lengths >= 1)
  }
}

extern "C" void kernel_launch(void* const* d_in, const int* in_sizes, int n_in,
                              void* d_out, int out_size, void* d_ws, size_t ws_size,
                              hipStream_t stream) {
  const float* enc  = (const float*)d_in[0];
  const int*   lens = (const int*)d_in[1];
  const float* Wh   = (const float*)d_in[2];
  const float* bh   = (const float*)d_in[3];
  const float* Wc   = (const float*)d_in[4];
  float* out = (float*)d_out;

  // C=32 (Lc=64): kernel assumes single 64-row pass per item. Workspace demand
  // (3*32*32*512*4 = 6.3MB + 1MB weights) is LOWER than every prior passing round.
  const int C = 32;
  const int Lc = LL / C;

  float* pm = (float*)d_ws;
  float* ps = pm + (size_t)BB * C * EE;
  float* po = ps + (size_t)BB * C * EE;
  unsigned short* WhT = (unsigned short*)(po + (size_t)BB * C * EE);
  unsigned short* WcT = WhT + (size_t)512 * 512;
  int* q = (int*)(WcT + (size_t)512 * 512);

  prep_w<<<dim3(64, 2), 256, 0, stream>>>(Wh, Wc, WhT, WcT, q);
  attn_main<<<dim3(256), 512, 0, stream>>>(enc, lens, WhT, bh, WcT, pm, ps, po, q, C, Lc);
  attn_combine<<<dim3(8, BB), 256, 0, stream>>>(pm, ps, po, lens, out, C, Lc);
}